// Round 8
// baseline (214.621 us; speedup 1.0000x reference)
//
#include <hip/hip_runtime.h>
#include <hip/hip_bf16.h>
#include <math.h>

#define BATCH 8
#define CI    256
#define HWSZ  1600
#define DDIM  128
#define NHEAD 8
#define DH    16
#define NPTS  32768

typedef __attribute__((ext_vector_type(4))) short s16x4;
typedef __attribute__((ext_vector_type(4))) float f32x4;

#if defined(__HIP_DEVICE_COMPILE__)
  #if __has_builtin(__builtin_amdgcn_mfma_f32_16x16x16bf16_1k)
    #define MFMA16(a, b, c) __builtin_amdgcn_mfma_f32_16x16x16bf16_1k(a, b, c, 0, 0, 0)
  #elif __has_builtin(__builtin_amdgcn_mfma_f32_16x16x16_bf16)
    #define MFMA16(a, b, c) __builtin_amdgcn_mfma_f32_16x16x16_bf16(a, b, c, 0, 0, 0)
  #else
    #error "no 16x16x16 bf16 mfma builtin on this device target"
  #endif
  #if __has_builtin(__builtin_amdgcn_exp2f)
    #define EXP2(x) __builtin_amdgcn_exp2f(x)
  #else
    #define EXP2(x) exp2f(x)
  #endif
#else
  #define MFMA16(a, b, c) (c)
  #define EXP2(x) (x)
#endif

union fragu {
  s16x4 s;
  unsigned int u[2];
  uint2 u2;
};

__device__ __forceinline__ unsigned int pk_bf2(float a, float b) {
  __hip_bfloat162 h = __float22bfloat162_rn(make_float2(a, b));
  return *(unsigned int*)&h;
}
__device__ __forceinline__ float bf2f(unsigned short u) {
  return __uint_as_float(((unsigned int)u) << 16);
}

// ---------------- KPREP: blocks 0..63 = weight gather; 64..575 = cloud ---
// W1s[dt][ks][lane]: A-frag bf16 of W1^T; W2s[ct][ks][lane]: A-frag of W2^T.
// Cloud part: 512 blocks x 64 rows (2 blocks/CU; R4's 256x128 was 1/CU and
// latency-bound on its serial 128-row pass) — l2norm rows + per-block GeM
// partials, write-once, no global atomics.
__global__ __launch_bounds__(256) void kprep(
    const float* __restrict__ W1, const float* __restrict__ W2,
    const float* __restrict__ cf, const int* __restrict__ bids,
    unsigned short* __restrict__ W1s, unsigned short* __restrict__ W2s,
    float* __restrict__ cloud_out, float* __restrict__ gaw,
    float* __restrict__ cntw) {
  __shared__ float ga[BATCH * DDIM];
  __shared__ float gc[BATCH];
  int t = threadIdx.x;
  if (blockIdx.x < 64) {
    int e = blockIdx.x * 256 + t;             // 16384 entries
    int lane = e & 63, lm = lane & 15, qd = lane >> 4;
    if (e < 8192) {
      int ks = (e >> 6) & 15, dt = e >> 10;
      const float* p = W1 + (size_t)(ks * 16 + 4 * qd) * DDIM + dt * 16 + lm;
      float f0 = p[0], f1 = p[DDIM], f2 = p[2 * DDIM], f3 = p[3 * DDIM];
      *(uint2*)&W1s[(size_t)e * 4] = make_uint2(pk_bf2(f0, f1), pk_bf2(f2, f3));
    } else {
      int e2 = e - 8192;
      int ks = (e2 >> 6) & 7, ct = e2 >> 9;
      const float* p = W2 + (size_t)(ks * 16 + 4 * qd) * CI + ct * 16 + lm;
      float f0 = p[0], f1 = p[CI], f2 = p[2 * CI], f3 = p[3 * CI];
      *(uint2*)&W2s[(size_t)e2 * 4] = make_uint2(pk_bf2(f0, f1), pk_bf2(f2, f3));
    }
    return;
  }
  int bk = blockIdx.x - 64;                   // 0..511, 64 rows each
  for (int i = t; i < BATCH * DDIM; i += 256) ga[i] = 0.f;
  if (t < BATCH) gc[t] = 0.f;
  __syncthreads();
  {
    int r = bk * 64 + (t >> 2);
    int dq = (t & 3) * 32;
    const float* row = cf + (size_t)r * DDIM + dq;
    float4 v[8];
    float ss = 0.f;
#pragma unroll
    for (int j = 0; j < 8; j++) {
      v[j] = *(const float4*)(row + j * 4);
      ss += v[j].x*v[j].x + v[j].y*v[j].y + v[j].z*v[j].z + v[j].w*v[j].w;
    }
    ss += __shfl_xor(ss, 1);
    ss += __shfl_xor(ss, 2);
    float sc = 1.f / fmaxf(sqrtf(ss), 1e-12f);
    int bid = bids[r];
    if ((t & 3) == 0) atomicAdd(&gc[bid], 1.f);
    float* orow = cloud_out + (size_t)r * DDIM + dq;
    float* gb = &ga[bid * DDIM + dq];
#pragma unroll
    for (int j = 0; j < 8; j++) {
      float4 y;
      y.x = v[j].x * sc; y.y = v[j].y * sc; y.z = v[j].z * sc; y.w = v[j].w * sc;
      *(float4*)(orow + j * 4) = y;
      float c0 = fmaxf(y.x, 1e-6f), c1 = fmaxf(y.y, 1e-6f);
      float c2 = fmaxf(y.z, 1e-6f), c3 = fmaxf(y.w, 1e-6f);
      atomicAdd(&gb[j*4+0], c0*c0*c0);
      atomicAdd(&gb[j*4+1], c1*c1*c1);
      atomicAdd(&gb[j*4+2], c2*c2*c2);
      atomicAdd(&gb[j*4+3], c3*c3*c3);
    }
  }
  __syncthreads();
  for (int i = t; i < BATCH * DDIM; i += 256) gaw[(size_t)bk * 1024 + i] = ga[i];
  if (t < BATCH) cntw[bk * 8 + t] = gc[t];
}

// ---------------- K1: MFMA linear1 + l2norm -> tokh bf16 [B,8,1600,16] ---
// 4 waves/block, full B-prefetch (64 loads) before the MFMA chain so HBM
// latency is paid once per wave, not per k-step.
__global__ __launch_bounds__(256) void k1_mfma(
    const float* __restrict__ img, const unsigned short* __restrict__ W1s,
    const float* __restrict__ b1, unsigned short* __restrict__ tokh) {
  int t = threadIdx.x, lane = t & 63, w = t >> 6;
  int lm = lane & 15, qd = lane >> 4;
  int blk = blockIdx.x;                      // 200 = 8b x 25 strips of 64
  int b = blk / 25, n0 = (blk % 25) * 64;
  int tok = n0 + w * 16 + lm;
  const float* imgb = img + (size_t)b * CI * HWSZ;
  const s16x4* W1s4 = (const s16x4*)W1s;
  float fv[16][4];
#pragma unroll
  for (int ks = 0; ks < 16; ks++) {
    const float* p = imgb + (size_t)(ks * 16 + 4 * qd) * HWSZ + tok;
    fv[ks][0] = p[0];        fv[ks][1] = p[HWSZ];
    fv[ks][2] = p[2 * HWSZ]; fv[ks][3] = p[3 * HWSZ];
  }
  f32x4 acc[8];
#pragma unroll
  for (int dt = 0; dt < 8; dt++) acc[dt] = (f32x4){0.f, 0.f, 0.f, 0.f};
#pragma unroll
  for (int ks = 0; ks < 16; ks++) {
    fragu bf_;
    bf_.u[0] = pk_bf2(fv[ks][0], fv[ks][1]);
    bf_.u[1] = pk_bf2(fv[ks][2], fv[ks][3]);
#pragma unroll
    for (int dt = 0; dt < 8; dt++) {
      s16x4 af = W1s4[(dt * 16 + ks) * 64 + lane];
      acc[dt] = MFMA16(af, bf_.s, acc[dt]);
    }
  }
  float vals[8][4];
  float ss = 0.f;
#pragma unroll
  for (int dt = 0; dt < 8; dt++)
#pragma unroll
    for (int r = 0; r < 4; r++) {
      float v = acc[dt][r] + b1[dt * 16 + 4 * qd + r];
      vals[dt][r] = v;
      ss += v * v;
    }
  ss += __shfl_xor(ss, 16);
  ss += __shfl_xor(ss, 32);
  float inv = 1.f / fmaxf(sqrtf(ss), 1e-12f);
#pragma unroll
  for (int dt = 0; dt < 8; dt++) {
    uint2 pk = make_uint2(pk_bf2(vals[dt][0] * inv, vals[dt][1] * inv),
                          pk_bf2(vals[dt][2] * inv, vals[dt][3] * inv));
    *(uint2*)&tokh[(((size_t)b * NHEAD + dt) * HWSZ + tok) * DH + 4 * qd] = pk;
  }
}

// ---------------- K2: MFMA flash attention, key-split 4x (R4 winner) -----
// grid (256,4): x = bh*4 + kc. Each 8-wave block stages 400 keys (32.25 KB
// LDS) -> 4 blocks/CU = 32 waves/CU = 8 waves/SIMD (HW cap). Balanced
// q-tiling: 25 tiles of 16; every wave runs 3 chains (ti = w+8s), one
// rotated wave (w == wx) takes tile 24. den accumulated on the MFMA pipe
// via ones-fragment; (num, den) partials combined in k3.
#define NKC4     400
#define XK_STR   24
#define VT_STR   408
__global__ __launch_bounds__(512) void k2_attn(
    const unsigned short* __restrict__ tokh, float* __restrict__ numw,
    float* __restrict__ denw) {
  __shared__ unsigned short sXk[NKC4 * XK_STR];   // 19200 B
  __shared__ unsigned short sVt[16 * VT_STR];     // 13056 B -> 32256 B total
  const int gx = blockIdx.x;
  const int bh = gx >> 2, kc = gx & 3;
  const int strip = blockIdx.y;                   // 0..3, 400 queries each
  const int t = threadIdx.x;
  const int lane = t & 63;
  const int w = t >> 6;                           // 0..7
  const int lm = lane & 15;
  const int qd = lane >> 4;
  const int wx = (kc + strip * 4) & 7;            // wave owning tile 24
  const unsigned short* tok = tokh + (size_t)bh * (HWSZ * DH);

  // stage this block's 400 keys (token-major for K, dim-major for V^T)
  for (int r = t; r < NKC4; r += 512) {
    const uint4* src = (const uint4*)(tok + (size_t)(kc * NKC4 + r) * DH);
    union { uint4 u4[2]; unsigned short us[16]; } uu;
    uu.u4[0] = src[0]; uu.u4[1] = src[1];
    *(uint4*)&sXk[r * XK_STR]     = uu.u4[0];
    *(uint4*)&sXk[r * XK_STR + 8] = uu.u4[1];
#pragma unroll
    for (int d = 0; d < 16; d++) sVt[d * VT_STR + r] = uu.us[d];
  }

  const float SCL = 0.25f * 1.44269504088896f;
  s16x4 qf[4];
  f32x4 oacc[4], dacc[4];
#pragma unroll
  for (int s = 0; s < 4; s++) {
    oacc[s] = (f32x4){0.f, 0.f, 0.f, 0.f};
    dacc[s] = (f32x4){0.f, 0.f, 0.f, 0.f};
    int ti = (s < 3) ? (w + 8 * s) : 24;
    if (s < 3 || w == wx) {
      int q = strip * 400 + ti * 16 + lm;
      const unsigned short* qs = tok + (size_t)q * DH + 4 * qd;
      s16x4 raw = *(const s16x4*)qs;
      fragu qq;
      qq.u[0] = pk_bf2(bf2f((unsigned short)raw[0]) * SCL,
                       bf2f((unsigned short)raw[1]) * SCL);
      qq.u[1] = pk_bf2(bf2f((unsigned short)raw[2]) * SCL,
                       bf2f((unsigned short)raw[3]) * SCL);
      qf[s] = qq.s;
    }
  }
  __syncthreads();

  fragu ones;
  ones.u[0] = 0x3F803F80u;  // bf16 1.0 x2
  ones.u[1] = 0x3F803F80u;
#pragma unroll 2
  for (int st = 0; st < NKC4 / 16; st++) {
    int n0 = st * 16;
    s16x4 kf = *(const s16x4*)&sXk[(n0 + lm) * XK_STR + 4 * qd];
    s16x4 vf = *(const s16x4*)&sVt[lm * VT_STR + n0 + 4 * qd];
#pragma unroll
    for (int s = 0; s < 3; s++) {                 // ti = w+8s <= 23: always valid
      f32x4 sc = MFMA16(kf, qf[s], ((f32x4){0.f, 0.f, 0.f, 0.f}));
      float e0 = EXP2(sc.x), e1 = EXP2(sc.y), e2 = EXP2(sc.z), e3 = EXP2(sc.w);
      fragu pf;
      pf.u[0] = pk_bf2(e0, e1);
      pf.u[1] = pk_bf2(e2, e3);
      dacc[s] = MFMA16(ones.s, pf.s, dacc[s]);    // den on the MFMA pipe
      oacc[s] = MFMA16(vf, pf.s, oacc[s]);
    }
    if (w == wx) {                                // tile 24: rotated wave only
      f32x4 sc = MFMA16(kf, qf[3], ((f32x4){0.f, 0.f, 0.f, 0.f}));
      float e0 = EXP2(sc.x), e1 = EXP2(sc.y), e2 = EXP2(sc.z), e3 = EXP2(sc.w);
      fragu pf;
      pf.u[0] = pk_bf2(e0, e1);
      pf.u[1] = pk_bf2(e2, e3);
      dacc[3] = MFMA16(ones.s, pf.s, dacc[3]);
      oacc[3] = MFMA16(vf, pf.s, oacc[3]);
    }
  }

#pragma unroll
  for (int s = 0; s < 4; s++) {
    int ti = (s < 3) ? (w + 8 * s) : 24;
    if (s < 3 || w == wx) {
      size_t q = (size_t)strip * 400 + ti * 16 + lm;
      float* np = numw + (((size_t)bh * 4 + kc) * HWSZ + q) * 16 + 4 * qd;
      *(f32x4*)np = oacc[s];
      if (qd == 0) denw[((size_t)bh * 4 + kc) * HWSZ + q] = dacc[s][0];
    }
  }
}

// ---------------- K3: combine attn partials + MFMA linear2 ---------------
// B-frag (ks, qd) spans head h = ks, dims 4qd..4qd+3: combine the 4 key-
// split partials (Σn / Σd) in-register, then 16 MFMAs per ks.
__global__ __launch_bounds__(256) void k3_mfma(
    const float* __restrict__ numw, const float* __restrict__ denw,
    const unsigned short* __restrict__ W2s, const float* __restrict__ b2,
    float* __restrict__ img_out) {
  int t = threadIdx.x, lane = t & 63, w = t >> 6;
  int lm = lane & 15, qd = lane >> 4;
  int blk = blockIdx.x;                      // 200 = 8b x 25 strips of 64
  int b = blk / 25, n0 = (blk % 25) * 64;
  int tok = n0 + w * 16 + lm;
  const s16x4* W2s4 = (const s16x4*)W2s;
  f32x4 acc[16];
#pragma unroll
  for (int ct = 0; ct < 16; ct++) acc[ct] = (f32x4){0.f, 0.f, 0.f, 0.f};
#pragma unroll 2
  for (int ks = 0; ks < 8; ks++) {
    size_t bh4 = (size_t)(b * 8 + ks) * 4;
    const float* npb = numw + (bh4 * HWSZ + tok) * 16 + 4 * qd;
    const float* dpb = denw + bh4 * HWSZ + tok;
    f32x4 nv0 = *(const f32x4*)npb;
    f32x4 nv1 = *(const f32x4*)(npb + (size_t)HWSZ * 16);
    f32x4 nv2 = *(const f32x4*)(npb + (size_t)HWSZ * 32);
    f32x4 nv3 = *(const f32x4*)(npb + (size_t)HWSZ * 48);
    float d = dpb[0] + dpb[HWSZ] + dpb[2 * HWSZ] + dpb[3 * HWSZ];
    float inv = 1.f / d;
    f32x4 nv;
    nv.x = (nv0.x + nv1.x) + (nv2.x + nv3.x);
    nv.y = (nv0.y + nv1.y) + (nv2.y + nv3.y);
    nv.z = (nv0.z + nv1.z) + (nv2.z + nv3.z);
    nv.w = (nv0.w + nv1.w) + (nv2.w + nv3.w);
    fragu bf_;
    bf_.u[0] = pk_bf2(nv.x * inv, nv.y * inv);
    bf_.u[1] = pk_bf2(nv.z * inv, nv.w * inv);
#pragma unroll
    for (int ct = 0; ct < 16; ct++) {
      s16x4 af = W2s4[(ct * 8 + ks) * 64 + lane];
      acc[ct] = MFMA16(af, bf_.s, acc[ct]);
    }
  }
  float* ob = img_out + (size_t)b * CI * HWSZ;
#pragma unroll
  for (int ct = 0; ct < 16; ct++)
#pragma unroll
    for (int r = 0; r < 4; r++) {
      int ci = ct * 16 + 4 * qd + r;
      ob[(size_t)ci * HWSZ + tok] = acc[ct][r] + b2[ci];
    }
}

// ---------------- KPOST: image GeM rows + cloud GeM combine --------------
__global__ __launch_bounds__(256) void kpost(
    const float* __restrict__ img_out, const float* __restrict__ gaw,
    const float* __restrict__ cntw, float* __restrict__ image_gem,
    float* __restrict__ cloud_gem) {
  __shared__ float cs[BATCH];
  int t = threadIdx.x;
  if (blockIdx.x < 512) {
    int w = t >> 6, lane = t & 63;
    int row = blockIdx.x * 4 + w;            // 2048 rows of 1600
    const float* r = img_out + (size_t)row * HWSZ;
    float s = 0.f;
    for (int i = lane; i < HWSZ; i += 64) {
      float c = fmaxf(r[i], 1e-6f);
      s += c * c * c;
    }
    s += __shfl_xor(s, 1);  s += __shfl_xor(s, 2);  s += __shfl_xor(s, 4);
    s += __shfl_xor(s, 8);  s += __shfl_xor(s, 16); s += __shfl_xor(s, 32);
    if (lane == 0) image_gem[row] = powf(s * (1.f / (float)HWSZ), 1.f / 3.f);
  } else {
    int j = (blockIdx.x - 512) * 256 + t;    // 0..1023
    if (t < BATCH) {
      float s = 0.f;
      for (int k = 0; k < 512; k++) s += cntw[k * 8 + t];
      cs[t] = s;
    }
    __syncthreads();
    float s = 0.f;
#pragma unroll 4
    for (int k = 0; k < 512; k++) s += gaw[(size_t)k * 1024 + j];
    int b = j >> 7;
    cloud_gem[j] = powf(s / fmaxf(cs[b], 1.f), 1.f / 3.f);
  }
}

extern "C" void kernel_launch(void* const* d_in, const int* in_sizes, int n_in,
                              void* d_out, int out_size, void* d_ws, size_t ws_size,
                              hipStream_t stream) {
  const float* image_feat = (const float*)d_in[0];
  const float* cloud_feat = (const float*)d_in[1];
  const int*   cloud_bids = (const int*)d_in[2];
  const float* W1 = (const float*)d_in[3];
  const float* b1 = (const float*)d_in[4];
  const float* W2 = (const float*)d_in[5];
  const float* b2 = (const float*)d_in[6];

  float* out = (float*)d_out;
  float* img_out   = out;                                  // [8,256,40,40]
  float* cloud_out = out + 3276800;                        // [32768,128]
  float* image_gem = out + 3276800 + 4194304;              // [8,256]
  float* cloud_gem = image_gem + 2048;                     // [8,128]

  char* ws = (char*)d_ws;
  unsigned short* tokh = (unsigned short*)ws;              //  3,276,800 B
  float* numw = (float*)(ws + 3276800);                    // 26,214,400 B
  float* denw = (float*)(ws + 29491200);                   //  1,638,400 B
  unsigned short* W1s = (unsigned short*)(ws + 31129600);  //     65,536 B
  unsigned short* W2s = (unsigned short*)(ws + 31195136);  //     65,536 B
  float* gaw  = (float*)(ws + 31260672);                   //  2,097,152 B
  float* cntw = (float*)(ws + 33357824);                   //     16,384 B

  kprep<<<dim3(576), dim3(256), 0, stream>>>(W1, W2, cloud_feat, cloud_bids,
                                             W1s, W2s, cloud_out, gaw, cntw);
  k1_mfma<<<dim3(200), dim3(256), 0, stream>>>(image_feat, W1s, b1, tokh);
  k2_attn<<<dim3(256, 4), dim3(512), 0, stream>>>(tokh, numw, denw);
  k3_mfma<<<dim3(200), dim3(256), 0, stream>>>(numw, denw, W2s, b2, img_out);
  kpost<<<dim3(516), dim3(256), 0, stream>>>(img_out, gaw, cntw,
                                             image_gem, cloud_gem);
}

// Round 9
// 170.778 us; speedup vs baseline: 1.2567x; 1.2567x over previous
//
#include <hip/hip_runtime.h>
#include <hip/hip_bf16.h>
#include <math.h>

#define BATCH 8
#define CI    256
#define HWSZ  1600
#define DDIM  128
#define NHEAD 8
#define DH    16
#define NPTS  32768

typedef __attribute__((ext_vector_type(4))) short s16x4;
typedef __attribute__((ext_vector_type(4))) float f32x4;

#if defined(__HIP_DEVICE_COMPILE__)
  #if __has_builtin(__builtin_amdgcn_mfma_f32_16x16x16bf16_1k)
    #define MFMA16(a, b, c) __builtin_amdgcn_mfma_f32_16x16x16bf16_1k(a, b, c, 0, 0, 0)
  #elif __has_builtin(__builtin_amdgcn_mfma_f32_16x16x16_bf16)
    #define MFMA16(a, b, c) __builtin_amdgcn_mfma_f32_16x16x16_bf16(a, b, c, 0, 0, 0)
  #else
    #error "no 16x16x16 bf16 mfma builtin on this device target"
  #endif
  #if __has_builtin(__builtin_amdgcn_exp2f)
    #define EXP2(x) __builtin_amdgcn_exp2f(x)
  #else
    #define EXP2(x) exp2f(x)
  #endif
#else
  #define MFMA16(a, b, c) (c)
  #define EXP2(x) (x)
#endif

union fragu {
  s16x4 s;
  unsigned int u[2];
  uint2 u2;
};

__device__ __forceinline__ unsigned int pk_bf2(float a, float b) {
  __hip_bfloat162 h = __float22bfloat162_rn(make_float2(a, b));
  return *(unsigned int*)&h;
}
__device__ __forceinline__ float bf2f(unsigned short u) {
  return __uint_as_float(((unsigned int)u) << 16);
}

// ---------------- KPREP: blocks 0..63 = weight gather; 64..319 = cloud ---
// W1s[dt][ks][lane]: A-frag bf16 of W1^T; W2s[ct][ks][lane]: A-frag of W2^T.
// Cloud part: l2norm rows + per-block GeM partials (write-once, no atomics
// to global, no zero-init dependency). (R4-proven config.)
__global__ __launch_bounds__(256) void kprep(
    const float* __restrict__ W1, const float* __restrict__ W2,
    const float* __restrict__ cf, const int* __restrict__ bids,
    unsigned short* __restrict__ W1s, unsigned short* __restrict__ W2s,
    float* __restrict__ cloud_out, float* __restrict__ gaw,
    float* __restrict__ cntw) {
  __shared__ float ga[BATCH * DDIM];
  __shared__ float gc[BATCH];
  int t = threadIdx.x;
  if (blockIdx.x < 64) {
    int e = blockIdx.x * 256 + t;             // 16384 entries
    int lane = e & 63, lm = lane & 15, qd = lane >> 4;
    if (e < 8192) {
      int ks = (e >> 6) & 15, dt = e >> 10;
      const float* p = W1 + (size_t)(ks * 16 + 4 * qd) * DDIM + dt * 16 + lm;
      float f0 = p[0], f1 = p[DDIM], f2 = p[2 * DDIM], f3 = p[3 * DDIM];
      *(uint2*)&W1s[(size_t)e * 4] = make_uint2(pk_bf2(f0, f1), pk_bf2(f2, f3));
    } else {
      int e2 = e - 8192;
      int ks = (e2 >> 6) & 7, ct = e2 >> 9;
      const float* p = W2 + (size_t)(ks * 16 + 4 * qd) * CI + ct * 16 + lm;
      float f0 = p[0], f1 = p[CI], f2 = p[2 * CI], f3 = p[3 * CI];
      *(uint2*)&W2s[(size_t)e2 * 4] = make_uint2(pk_bf2(f0, f1), pk_bf2(f2, f3));
    }
    return;
  }
  int bk = blockIdx.x - 64;                   // 0..255, 128 rows each
  for (int i = t; i < BATCH * DDIM; i += 256) ga[i] = 0.f;
  if (t < BATCH) gc[t] = 0.f;
  __syncthreads();
  for (int half = 0; half < 2; half++) {
    int r = bk * 128 + half * 64 + (t >> 2);
    int dq = (t & 3) * 32;
    const float* row = cf + (size_t)r * DDIM + dq;
    float4 v[8];
    float ss = 0.f;
#pragma unroll
    for (int j = 0; j < 8; j++) {
      v[j] = *(const float4*)(row + j * 4);
      ss += v[j].x*v[j].x + v[j].y*v[j].y + v[j].z*v[j].z + v[j].w*v[j].w;
    }
    ss += __shfl_xor(ss, 1);
    ss += __shfl_xor(ss, 2);
    float sc = 1.f / fmaxf(sqrtf(ss), 1e-12f);
    int bid = bids[r];
    if ((t & 3) == 0) atomicAdd(&gc[bid], 1.f);
    float* orow = cloud_out + (size_t)r * DDIM + dq;
    float* gb = &ga[bid * DDIM + dq];
#pragma unroll
    for (int j = 0; j < 8; j++) {
      float4 y;
      y.x = v[j].x * sc; y.y = v[j].y * sc; y.z = v[j].z * sc; y.w = v[j].w * sc;
      *(float4*)(orow + j * 4) = y;
      float c0 = fmaxf(y.x, 1e-6f), c1 = fmaxf(y.y, 1e-6f);
      float c2 = fmaxf(y.z, 1e-6f), c3 = fmaxf(y.w, 1e-6f);
      atomicAdd(&gb[j*4+0], c0*c0*c0);
      atomicAdd(&gb[j*4+1], c1*c1*c1);
      atomicAdd(&gb[j*4+2], c2*c2*c2);
      atomicAdd(&gb[j*4+3], c3*c3*c3);
    }
  }
  __syncthreads();
  for (int i = t; i < BATCH * DDIM; i += 256) gaw[(size_t)bk * 1024 + i] = ga[i];
  if (t < BATCH) cntw[bk * 8 + t] = gc[t];
}

// ---------------- K1: MFMA linear1 + l2norm -> tokh bf16 [B,8,1600,16] ---
// 4 waves/block, full B-prefetch (64 loads) before the MFMA chain so HBM
// latency is paid once per wave, not per k-step.
__global__ __launch_bounds__(256) void k1_mfma(
    const float* __restrict__ img, const unsigned short* __restrict__ W1s,
    const float* __restrict__ b1, unsigned short* __restrict__ tokh) {
  int t = threadIdx.x, lane = t & 63, w = t >> 6;
  int lm = lane & 15, qd = lane >> 4;
  int blk = blockIdx.x;                      // 200 = 8b x 25 strips of 64
  int b = blk / 25, n0 = (blk % 25) * 64;
  int tok = n0 + w * 16 + lm;
  const float* imgb = img + (size_t)b * CI * HWSZ;
  const s16x4* W1s4 = (const s16x4*)W1s;
  float fv[16][4];
#pragma unroll
  for (int ks = 0; ks < 16; ks++) {
    const float* p = imgb + (size_t)(ks * 16 + 4 * qd) * HWSZ + tok;
    fv[ks][0] = p[0];        fv[ks][1] = p[HWSZ];
    fv[ks][2] = p[2 * HWSZ]; fv[ks][3] = p[3 * HWSZ];
  }
  f32x4 acc[8];
#pragma unroll
  for (int dt = 0; dt < 8; dt++) acc[dt] = (f32x4){0.f, 0.f, 0.f, 0.f};
#pragma unroll
  for (int ks = 0; ks < 16; ks++) {
    fragu bf_;
    bf_.u[0] = pk_bf2(fv[ks][0], fv[ks][1]);
    bf_.u[1] = pk_bf2(fv[ks][2], fv[ks][3]);
#pragma unroll
    for (int dt = 0; dt < 8; dt++) {
      s16x4 af = W1s4[(dt * 16 + ks) * 64 + lane];
      acc[dt] = MFMA16(af, bf_.s, acc[dt]);
    }
  }
  float vals[8][4];
  float ss = 0.f;
#pragma unroll
  for (int dt = 0; dt < 8; dt++)
#pragma unroll
    for (int r = 0; r < 4; r++) {
      float v = acc[dt][r] + b1[dt * 16 + 4 * qd + r];
      vals[dt][r] = v;
      ss += v * v;
    }
  ss += __shfl_xor(ss, 16);
  ss += __shfl_xor(ss, 32);
  float inv = 1.f / fmaxf(sqrtf(ss), 1e-12f);
#pragma unroll
  for (int dt = 0; dt < 8; dt++) {
    uint2 pk = make_uint2(pk_bf2(vals[dt][0] * inv, vals[dt][1] * inv),
                          pk_bf2(vals[dt][2] * inv, vals[dt][3] * inv));
    *(uint2*)&tokh[(((size_t)b * NHEAD + dt) * HWSZ + tok) * DH + 4 * qd] = pk;
  }
}

// ---------------- K2: MFMA flash attention, key-split 4x (R4 winner) -----
// grid (256,4): x = bh*4 + kc. Each 8-wave block stages 400 keys (32.25 KB
// LDS) -> 4 blocks/CU = 32 waves/CU = 8 waves/SIMD (HW cap). Balanced
// q-tiling: 25 tiles of 16; every wave runs 3 chains (ti = w+8s), one
// rotated wave (w == wx) takes tile 24. den accumulated on the MFMA pipe
// via ones-fragment; (num, den) partials combined in k3.
#define NKC4     400
#define XK_STR   24
#define VT_STR   408
__global__ __launch_bounds__(512) void k2_attn(
    const unsigned short* __restrict__ tokh, float* __restrict__ numw,
    float* __restrict__ denw) {
  __shared__ unsigned short sXk[NKC4 * XK_STR];   // 19200 B
  __shared__ unsigned short sVt[16 * VT_STR];     // 13056 B -> 32256 B total
  const int gx = blockIdx.x;
  const int bh = gx >> 2, kc = gx & 3;
  const int strip = blockIdx.y;                   // 0..3, 400 queries each
  const int t = threadIdx.x;
  const int lane = t & 63;
  const int w = t >> 6;                           // 0..7
  const int lm = lane & 15;
  const int qd = lane >> 4;
  const int wx = (kc + strip * 4) & 7;            // wave owning tile 24
  const unsigned short* tok = tokh + (size_t)bh * (HWSZ * DH);

  // stage this block's 400 keys (token-major for K, dim-major for V^T)
  for (int r = t; r < NKC4; r += 512) {
    const uint4* src = (const uint4*)(tok + (size_t)(kc * NKC4 + r) * DH);
    union { uint4 u4[2]; unsigned short us[16]; } uu;
    uu.u4[0] = src[0]; uu.u4[1] = src[1];
    *(uint4*)&sXk[r * XK_STR]     = uu.u4[0];
    *(uint4*)&sXk[r * XK_STR + 8] = uu.u4[1];
#pragma unroll
    for (int d = 0; d < 16; d++) sVt[d * VT_STR + r] = uu.us[d];
  }

  const float SCL = 0.25f * 1.44269504088896f;
  s16x4 qf[4];
  f32x4 oacc[4], dacc[4];
#pragma unroll
  for (int s = 0; s < 4; s++) {
    oacc[s] = (f32x4){0.f, 0.f, 0.f, 0.f};
    dacc[s] = (f32x4){0.f, 0.f, 0.f, 0.f};
    int ti = (s < 3) ? (w + 8 * s) : 24;
    if (s < 3 || w == wx) {
      int q = strip * 400 + ti * 16 + lm;
      const unsigned short* qs = tok + (size_t)q * DH + 4 * qd;
      s16x4 raw = *(const s16x4*)qs;
      fragu qq;
      qq.u[0] = pk_bf2(bf2f((unsigned short)raw[0]) * SCL,
                       bf2f((unsigned short)raw[1]) * SCL);
      qq.u[1] = pk_bf2(bf2f((unsigned short)raw[2]) * SCL,
                       bf2f((unsigned short)raw[3]) * SCL);
      qf[s] = qq.s;
    }
  }
  __syncthreads();

  fragu ones;
  ones.u[0] = 0x3F803F80u;  // bf16 1.0 x2
  ones.u[1] = 0x3F803F80u;
#pragma unroll 2
  for (int st = 0; st < NKC4 / 16; st++) {
    int n0 = st * 16;
    s16x4 kf = *(const s16x4*)&sXk[(n0 + lm) * XK_STR + 4 * qd];
    s16x4 vf = *(const s16x4*)&sVt[lm * VT_STR + n0 + 4 * qd];
#pragma unroll
    for (int s = 0; s < 3; s++) {                 // ti = w+8s <= 23: always valid
      f32x4 sc = MFMA16(kf, qf[s], ((f32x4){0.f, 0.f, 0.f, 0.f}));
      float e0 = EXP2(sc.x), e1 = EXP2(sc.y), e2 = EXP2(sc.z), e3 = EXP2(sc.w);
      fragu pf;
      pf.u[0] = pk_bf2(e0, e1);
      pf.u[1] = pk_bf2(e2, e3);
      dacc[s] = MFMA16(ones.s, pf.s, dacc[s]);    // den on the MFMA pipe
      oacc[s] = MFMA16(vf, pf.s, oacc[s]);
    }
    if (w == wx) {                                // tile 24: rotated wave only
      f32x4 sc = MFMA16(kf, qf[3], ((f32x4){0.f, 0.f, 0.f, 0.f}));
      float e0 = EXP2(sc.x), e1 = EXP2(sc.y), e2 = EXP2(sc.z), e3 = EXP2(sc.w);
      fragu pf;
      pf.u[0] = pk_bf2(e0, e1);
      pf.u[1] = pk_bf2(e2, e3);
      dacc[3] = MFMA16(ones.s, pf.s, dacc[3]);
      oacc[3] = MFMA16(vf, pf.s, oacc[3]);
    }
  }

#pragma unroll
  for (int s = 0; s < 4; s++) {
    int ti = (s < 3) ? (w + 8 * s) : 24;
    if (s < 3 || w == wx) {
      size_t q = (size_t)strip * 400 + ti * 16 + lm;
      float* np = numw + (((size_t)bh * 4 + kc) * HWSZ + q) * 16 + 4 * qd;
      *(f32x4*)np = oacc[s];
      if (qd == 0) denw[((size_t)bh * 4 + kc) * HWSZ + q] = dacc[s][0];
    }
  }
}

// ---------------- K3: combine attn partials + MFMA linear2 ---------------
// B-frag (ks, qd) spans head h = ks, dims 4qd..4qd+3: combine the 4 key-
// split partials (Σn / Σd) in-register, then 16 MFMAs per ks.
__global__ __launch_bounds__(256) void k3_mfma(
    const float* __restrict__ numw, const float* __restrict__ denw,
    const unsigned short* __restrict__ W2s, const float* __restrict__ b2,
    float* __restrict__ img_out) {
  int t = threadIdx.x, lane = t & 63, w = t >> 6;
  int lm = lane & 15, qd = lane >> 4;
  int blk = blockIdx.x;                      // 200 = 8b x 25 strips of 64
  int b = blk / 25, n0 = (blk % 25) * 64;
  int tok = n0 + w * 16 + lm;
  const s16x4* W2s4 = (const s16x4*)W2s;
  f32x4 acc[16];
#pragma unroll
  for (int ct = 0; ct < 16; ct++) acc[ct] = (f32x4){0.f, 0.f, 0.f, 0.f};
#pragma unroll 2
  for (int ks = 0; ks < 8; ks++) {
    size_t bh4 = (size_t)(b * 8 + ks) * 4;
    const float* npb = numw + (bh4 * HWSZ + tok) * 16 + 4 * qd;
    const float* dpb = denw + bh4 * HWSZ + tok;
    f32x4 nv0 = *(const f32x4*)npb;
    f32x4 nv1 = *(const f32x4*)(npb + (size_t)HWSZ * 16);
    f32x4 nv2 = *(const f32x4*)(npb + (size_t)HWSZ * 32);
    f32x4 nv3 = *(const f32x4*)(npb + (size_t)HWSZ * 48);
    float d = dpb[0] + dpb[HWSZ] + dpb[2 * HWSZ] + dpb[3 * HWSZ];
    float inv = 1.f / d;
    f32x4 nv;
    nv.x = (nv0.x + nv1.x) + (nv2.x + nv3.x);
    nv.y = (nv0.y + nv1.y) + (nv2.y + nv3.y);
    nv.z = (nv0.z + nv1.z) + (nv2.z + nv3.z);
    nv.w = (nv0.w + nv1.w) + (nv2.w + nv3.w);
    fragu bf_;
    bf_.u[0] = pk_bf2(nv.x * inv, nv.y * inv);
    bf_.u[1] = pk_bf2(nv.z * inv, nv.w * inv);
#pragma unroll
    for (int ct = 0; ct < 16; ct++) {
      s16x4 af = W2s4[(ct * 8 + ks) * 64 + lane];
      acc[ct] = MFMA16(af, bf_.s, acc[ct]);
    }
  }
  float* ob = img_out + (size_t)b * CI * HWSZ;
#pragma unroll
  for (int ct = 0; ct < 16; ct++)
#pragma unroll
    for (int r = 0; r < 4; r++) {
      int ci = ct * 16 + 4 * qd + r;
      ob[(size_t)ci * HWSZ + tok] = acc[ct][r] + b2[ci];
    }
}

// ---------------- KPOST: image GeM rows (float4) + cloud GeM combine -----
// Image: one wave per row, float4 loads (400 x 16 B -> 7 iters vs 25 scalar;
// R8 counters showed 142 GB/s latency-bound scalar version at 54 us).
// Cloud: 4 blocks x 64 float4-slots x 4 k-chunks, coalesced float4 loads,
// LDS combine; counts via 2 waves of strided loads + shfl reduce.
__global__ __launch_bounds__(256) void kpost(
    const float* __restrict__ img_out, const float* __restrict__ gaw,
    const float* __restrict__ cntw, float* __restrict__ image_gem,
    float* __restrict__ cloud_gem) {
  __shared__ float cs[2];
  __shared__ float4 part[3][64];
  int t = threadIdx.x;
  int w = t >> 6, lane = t & 63;
  if (blockIdx.x < 512) {
    int row = blockIdx.x * 4 + w;            // 2048 rows of 1600 (=400 float4)
    const float4* r4 = (const float4*)(img_out + (size_t)row * HWSZ);
    float s = 0.f;
    for (int i = lane; i < 400; i += 64) {
      float4 v = r4[i];
      float c0 = fmaxf(v.x, 1e-6f), c1 = fmaxf(v.y, 1e-6f);
      float c2 = fmaxf(v.z, 1e-6f), c3 = fmaxf(v.w, 1e-6f);
      s += (c0*c0*c0 + c1*c1*c1) + (c2*c2*c2 + c3*c3*c3);
    }
    s += __shfl_xor(s, 1);  s += __shfl_xor(s, 2);  s += __shfl_xor(s, 4);
    s += __shfl_xor(s, 8);  s += __shfl_xor(s, 16); s += __shfl_xor(s, 32);
    if (lane == 0) image_gem[row] = powf(s * (1.f / (float)HWSZ), 1.f / 3.f);
  } else {
    int bb = blockIdx.x - 512;               // 0..3: j range bb*256..bb*256+255
    int sl = lane;                           // local slot 0..63
    int slot = bb * 64 + sl;                 // global float4-slot 0..255
    int kc = w;                              // k-chunk 0..3
    const float4* g4 = (const float4*)gaw;   // [256 blocks][256 float4]
    float4 s4 = make_float4(0.f, 0.f, 0.f, 0.f);
#pragma unroll 4
    for (int k = kc * 64; k < kc * 64 + 64; k++) {
      float4 v = g4[(size_t)k * 256 + slot];
      s4.x += v.x; s4.y += v.y; s4.z += v.z; s4.w += v.w;
    }
    // counts: waves 0,1 each reduce one batch's 256 cntw entries
    if (w < 2) {
      int b = 2 * bb + w;
      float c = 0.f;
#pragma unroll 4
      for (int k = lane; k < 256; k += 64) c += cntw[k * 8 + b];
      c += __shfl_xor(c, 1);  c += __shfl_xor(c, 2);  c += __shfl_xor(c, 4);
      c += __shfl_xor(c, 8);  c += __shfl_xor(c, 16); c += __shfl_xor(c, 32);
      if (lane == 0) cs[w] = c;
    }
    if (kc != 0) part[kc - 1][sl] = s4;
    __syncthreads();
    if (kc == 0) {
      float4 p0 = part[0][sl], p1 = part[1][sl], p2 = part[2][sl];
      s4.x += (p0.x + p1.x) + p2.x;
      s4.y += (p0.y + p1.y) + p2.y;
      s4.z += (p0.z + p1.z) + p2.z;
      s4.w += (p0.w + p1.w) + p2.w;
      float inv = 1.f / fmaxf(cs[sl >> 5], 1.f);
      int j = slot * 4;
      cloud_gem[j + 0] = powf(s4.x * inv, 1.f / 3.f);
      cloud_gem[j + 1] = powf(s4.y * inv, 1.f / 3.f);
      cloud_gem[j + 2] = powf(s4.z * inv, 1.f / 3.f);
      cloud_gem[j + 3] = powf(s4.w * inv, 1.f / 3.f);
    }
  }
}

extern "C" void kernel_launch(void* const* d_in, const int* in_sizes, int n_in,
                              void* d_out, int out_size, void* d_ws, size_t ws_size,
                              hipStream_t stream) {
  const float* image_feat = (const float*)d_in[0];
  const float* cloud_feat = (const float*)d_in[1];
  const int*   cloud_bids = (const int*)d_in[2];
  const float* W1 = (const float*)d_in[3];
  const float* b1 = (const float*)d_in[4];
  const float* W2 = (const float*)d_in[5];
  const float* b2 = (const float*)d_in[6];

  float* out = (float*)d_out;
  float* img_out   = out;                                  // [8,256,40,40]
  float* cloud_out = out + 3276800;                        // [32768,128]
  float* image_gem = out + 3276800 + 4194304;              // [8,256]
  float* cloud_gem = image_gem + 2048;                     // [8,128]

  char* ws = (char*)d_ws;
  unsigned short* tokh = (unsigned short*)ws;              //  3,276,800 B
  float* numw = (float*)(ws + 3276800);                    // 26,214,400 B
  float* denw = (float*)(ws + 29491200);                   //  1,638,400 B
  unsigned short* W1s = (unsigned short*)(ws + 31129600);  //     65,536 B
  unsigned short* W2s = (unsigned short*)(ws + 31195136);  //     65,536 B
  float* gaw  = (float*)(ws + 31260672);                   //  1,048,576 B
  float* cntw = (float*)(ws + 32309248);                   //      8,192 B

  kprep<<<dim3(320), dim3(256), 0, stream>>>(W1, W2, cloud_feat, cloud_bids,
                                             W1s, W2s, cloud_out, gaw, cntw);
  k1_mfma<<<dim3(200), dim3(256), 0, stream>>>(image_feat, W1s, b1, tokh);
  k2_attn<<<dim3(256, 4), dim3(512), 0, stream>>>(tokh, numw, denw);
  k3_mfma<<<dim3(200), dim3(256), 0, stream>>>(numw, denw, W2s, b2, img_out);
  kpost<<<dim3(516), dim3(256), 0, stream>>>(img_out, gaw, cntw,
                                             image_gem, cloud_gem);
}

// Round 10
// 163.172 us; speedup vs baseline: 1.3153x; 1.0466x over previous
//
#include <hip/hip_runtime.h>
#include <hip/hip_bf16.h>
#include <math.h>

#define BATCH 8
#define CI    256
#define HWSZ  1600
#define DDIM  128
#define NHEAD 8
#define DH    16
#define NPTS  32768

typedef __attribute__((ext_vector_type(4))) short s16x4;
typedef __attribute__((ext_vector_type(4))) float f32x4;

#if defined(__HIP_DEVICE_COMPILE__)
  #if __has_builtin(__builtin_amdgcn_mfma_f32_16x16x16bf16_1k)
    #define MFMA16(a, b, c) __builtin_amdgcn_mfma_f32_16x16x16bf16_1k(a, b, c, 0, 0, 0)
  #elif __has_builtin(__builtin_amdgcn_mfma_f32_16x16x16_bf16)
    #define MFMA16(a, b, c) __builtin_amdgcn_mfma_f32_16x16x16_bf16(a, b, c, 0, 0, 0)
  #else
    #error "no 16x16x16 bf16 mfma builtin on this device target"
  #endif
  #if __has_builtin(__builtin_amdgcn_exp2f)
    #define EXP2(x) __builtin_amdgcn_exp2f(x)
  #else
    #define EXP2(x) exp2f(x)
  #endif
#else
  #define MFMA16(a, b, c) (c)
  #define EXP2(x) (x)
#endif

union fragu {
  s16x4 s;
  unsigned int u[2];
  uint2 u2;
};

__device__ __forceinline__ unsigned int pk_bf2(float a, float b) {
  __hip_bfloat162 h = __float22bfloat162_rn(make_float2(a, b));
  return *(unsigned int*)&h;
}
__device__ __forceinline__ float bf2f(unsigned short u) {
  return __uint_as_float(((unsigned int)u) << 16);
}

// ---------------- KPREP: 64 blocks of weight gather only -----------------
// W1s[dt][ks][lane]: A-frag bf16 of W1^T; W2s[ct][ks][lane]: A-frag of W2^T.
// Cloud branch moved into k1's grid (it has no dependency on weights and
// k1's 200 image blocks leave 56+ CUs idle).
__global__ __launch_bounds__(256) void kprep(
    const float* __restrict__ W1, const float* __restrict__ W2,
    unsigned short* __restrict__ W1s, unsigned short* __restrict__ W2s) {
  int t = threadIdx.x;
  int e = blockIdx.x * 256 + t;             // 16384 entries
  int lane = e & 63, lm = lane & 15, qd = lane >> 4;
  if (e < 8192) {
    int ks = (e >> 6) & 15, dt = e >> 10;
    const float* p = W1 + (size_t)(ks * 16 + 4 * qd) * DDIM + dt * 16 + lm;
    float f0 = p[0], f1 = p[DDIM], f2 = p[2 * DDIM], f3 = p[3 * DDIM];
    *(uint2*)&W1s[(size_t)e * 4] = make_uint2(pk_bf2(f0, f1), pk_bf2(f2, f3));
  } else {
    int e2 = e - 8192;
    int ks = (e2 >> 6) & 7, ct = e2 >> 9;
    const float* p = W2 + (size_t)(ks * 16 + 4 * qd) * CI + ct * 16 + lm;
    float f0 = p[0], f1 = p[CI], f2 = p[2 * CI], f3 = p[3 * CI];
    *(uint2*)&W2s[(size_t)e2 * 4] = make_uint2(pk_bf2(f0, f1), pk_bf2(f2, f3));
  }
}

// ---------------- K1: MFMA linear1 + l2norm -> tokh; + cloud branch ------
// blocks 0..199: image branch (4 waves, full B-prefetch before MFMA chain).
// blocks 200..455: cloud branch (l2norm + per-block GeM partials) — fused
// here so the cloud work runs on the CUs k1's 200 blocks leave idle
// (R1-proven structure; cloud math identical to the R4/R9 kprep branch).
__global__ __launch_bounds__(256) void k1_mfma(
    const float* __restrict__ img, const unsigned short* __restrict__ W1s,
    const float* __restrict__ b1, unsigned short* __restrict__ tokh,
    const float* __restrict__ cf, const int* __restrict__ bids,
    float* __restrict__ cloud_out, float* __restrict__ gaw,
    float* __restrict__ cntw) {
  __shared__ float ga[BATCH * DDIM];
  __shared__ float gc[BATCH];
  int t = threadIdx.x;
  if (blockIdx.x >= 200) {
    // ---------- cloud branch ----------
    int bk = blockIdx.x - 200;               // 0..255, 128 rows each
    for (int i = t; i < BATCH * DDIM; i += 256) ga[i] = 0.f;
    if (t < BATCH) gc[t] = 0.f;
    __syncthreads();
    for (int half = 0; half < 2; half++) {
      int r = bk * 128 + half * 64 + (t >> 2);
      int dq = (t & 3) * 32;
      const float* row = cf + (size_t)r * DDIM + dq;
      float4 v[8];
      float ss = 0.f;
#pragma unroll
      for (int j = 0; j < 8; j++) {
        v[j] = *(const float4*)(row + j * 4);
        ss += v[j].x*v[j].x + v[j].y*v[j].y + v[j].z*v[j].z + v[j].w*v[j].w;
      }
      ss += __shfl_xor(ss, 1);
      ss += __shfl_xor(ss, 2);
      float sc = 1.f / fmaxf(sqrtf(ss), 1e-12f);
      int bid = bids[r];
      if ((t & 3) == 0) atomicAdd(&gc[bid], 1.f);
      float* orow = cloud_out + (size_t)r * DDIM + dq;
      float* gb = &ga[bid * DDIM + dq];
#pragma unroll
      for (int j = 0; j < 8; j++) {
        float4 y;
        y.x = v[j].x * sc; y.y = v[j].y * sc; y.z = v[j].z * sc; y.w = v[j].w * sc;
        *(float4*)(orow + j * 4) = y;
        float c0 = fmaxf(y.x, 1e-6f), c1 = fmaxf(y.y, 1e-6f);
        float c2 = fmaxf(y.z, 1e-6f), c3 = fmaxf(y.w, 1e-6f);
        atomicAdd(&gb[j*4+0], c0*c0*c0);
        atomicAdd(&gb[j*4+1], c1*c1*c1);
        atomicAdd(&gb[j*4+2], c2*c2*c2);
        atomicAdd(&gb[j*4+3], c3*c3*c3);
      }
    }
    __syncthreads();
    for (int i = t; i < BATCH * DDIM; i += 256) gaw[(size_t)bk * 1024 + i] = ga[i];
    if (t < BATCH) cntw[bk * 8 + t] = gc[t];
    return;
  }
  // ---------- image branch ----------
  int lane = t & 63, w = t >> 6;
  int lm = lane & 15, qd = lane >> 4;
  int blk = blockIdx.x;                      // 200 = 8b x 25 strips of 64
  int b = blk / 25, n0 = (blk % 25) * 64;
  int tok = n0 + w * 16 + lm;
  const float* imgb = img + (size_t)b * CI * HWSZ;
  const s16x4* W1s4 = (const s16x4*)W1s;
  float fv[16][4];
#pragma unroll
  for (int ks = 0; ks < 16; ks++) {
    const float* p = imgb + (size_t)(ks * 16 + 4 * qd) * HWSZ + tok;
    fv[ks][0] = p[0];        fv[ks][1] = p[HWSZ];
    fv[ks][2] = p[2 * HWSZ]; fv[ks][3] = p[3 * HWSZ];
  }
  f32x4 acc[8];
#pragma unroll
  for (int dt = 0; dt < 8; dt++) acc[dt] = (f32x4){0.f, 0.f, 0.f, 0.f};
#pragma unroll
  for (int ks = 0; ks < 16; ks++) {
    fragu bf_;
    bf_.u[0] = pk_bf2(fv[ks][0], fv[ks][1]);
    bf_.u[1] = pk_bf2(fv[ks][2], fv[ks][3]);
#pragma unroll
    for (int dt = 0; dt < 8; dt++) {
      s16x4 af = W1s4[(dt * 16 + ks) * 64 + lane];
      acc[dt] = MFMA16(af, bf_.s, acc[dt]);
    }
  }
  float vals[8][4];
  float ss = 0.f;
#pragma unroll
  for (int dt = 0; dt < 8; dt++)
#pragma unroll
    for (int r = 0; r < 4; r++) {
      float v = acc[dt][r] + b1[dt * 16 + 4 * qd + r];
      vals[dt][r] = v;
      ss += v * v;
    }
  ss += __shfl_xor(ss, 16);
  ss += __shfl_xor(ss, 32);
  float inv = 1.f / fmaxf(sqrtf(ss), 1e-12f);
#pragma unroll
  for (int dt = 0; dt < 8; dt++) {
    uint2 pk = make_uint2(pk_bf2(vals[dt][0] * inv, vals[dt][1] * inv),
                          pk_bf2(vals[dt][2] * inv, vals[dt][3] * inv));
    *(uint2*)&tokh[(((size_t)b * NHEAD + dt) * HWSZ + tok) * DH + 4 * qd] = pk;
  }
}

// ---------------- K2: MFMA flash attention, key-split 4x (R4 winner) -----
// grid (256,4): x = bh*4 + kc. Each 8-wave block stages 400 keys (32.25 KB
// LDS) -> 4 blocks/CU = 32 waves/CU = 8 waves/SIMD (HW cap). Balanced
// q-tiling: 25 tiles of 16; every wave runs 3 chains (ti = w+8s), one
// rotated wave (w == wx) takes tile 24. den accumulated on the MFMA pipe
// via ones-fragment; (num, den) partials combined in k3.
#define NKC4     400
#define XK_STR   24
#define VT_STR   408
__global__ __launch_bounds__(512) void k2_attn(
    const unsigned short* __restrict__ tokh, float* __restrict__ numw,
    float* __restrict__ denw) {
  __shared__ unsigned short sXk[NKC4 * XK_STR];   // 19200 B
  __shared__ unsigned short sVt[16 * VT_STR];     // 13056 B -> 32256 B total
  const int gx = blockIdx.x;
  const int bh = gx >> 2, kc = gx & 3;
  const int strip = blockIdx.y;                   // 0..3, 400 queries each
  const int t = threadIdx.x;
  const int lane = t & 63;
  const int w = t >> 6;                           // 0..7
  const int lm = lane & 15;
  const int qd = lane >> 4;
  const int wx = (kc + strip * 4) & 7;            // wave owning tile 24
  const unsigned short* tok = tokh + (size_t)bh * (HWSZ * DH);

  // stage this block's 400 keys (token-major for K, dim-major for V^T)
  for (int r = t; r < NKC4; r += 512) {
    const uint4* src = (const uint4*)(tok + (size_t)(kc * NKC4 + r) * DH);
    union { uint4 u4[2]; unsigned short us[16]; } uu;
    uu.u4[0] = src[0]; uu.u4[1] = src[1];
    *(uint4*)&sXk[r * XK_STR]     = uu.u4[0];
    *(uint4*)&sXk[r * XK_STR + 8] = uu.u4[1];
#pragma unroll
    for (int d = 0; d < 16; d++) sVt[d * VT_STR + r] = uu.us[d];
  }

  const float SCL = 0.25f * 1.44269504088896f;
  s16x4 qf[4];
  f32x4 oacc[4], dacc[4];
#pragma unroll
  for (int s = 0; s < 4; s++) {
    oacc[s] = (f32x4){0.f, 0.f, 0.f, 0.f};
    dacc[s] = (f32x4){0.f, 0.f, 0.f, 0.f};
    int ti = (s < 3) ? (w + 8 * s) : 24;
    if (s < 3 || w == wx) {
      int q = strip * 400 + ti * 16 + lm;
      const unsigned short* qs = tok + (size_t)q * DH + 4 * qd;
      s16x4 raw = *(const s16x4*)qs;
      fragu qq;
      qq.u[0] = pk_bf2(bf2f((unsigned short)raw[0]) * SCL,
                       bf2f((unsigned short)raw[1]) * SCL);
      qq.u[1] = pk_bf2(bf2f((unsigned short)raw[2]) * SCL,
                       bf2f((unsigned short)raw[3]) * SCL);
      qf[s] = qq.s;
    }
  }
  __syncthreads();

  fragu ones;
  ones.u[0] = 0x3F803F80u;  // bf16 1.0 x2
  ones.u[1] = 0x3F803F80u;
#pragma unroll 2
  for (int st = 0; st < NKC4 / 16; st++) {
    int n0 = st * 16;
    s16x4 kf = *(const s16x4*)&sXk[(n0 + lm) * XK_STR + 4 * qd];
    s16x4 vf = *(const s16x4*)&sVt[lm * VT_STR + n0 + 4 * qd];
#pragma unroll
    for (int s = 0; s < 3; s++) {                 // ti = w+8s <= 23: always valid
      f32x4 sc = MFMA16(kf, qf[s], ((f32x4){0.f, 0.f, 0.f, 0.f}));
      float e0 = EXP2(sc.x), e1 = EXP2(sc.y), e2 = EXP2(sc.z), e3 = EXP2(sc.w);
      fragu pf;
      pf.u[0] = pk_bf2(e0, e1);
      pf.u[1] = pk_bf2(e2, e3);
      dacc[s] = MFMA16(ones.s, pf.s, dacc[s]);    // den on the MFMA pipe
      oacc[s] = MFMA16(vf, pf.s, oacc[s]);
    }
    if (w == wx) {                                // tile 24: rotated wave only
      f32x4 sc = MFMA16(kf, qf[3], ((f32x4){0.f, 0.f, 0.f, 0.f}));
      float e0 = EXP2(sc.x), e1 = EXP2(sc.y), e2 = EXP2(sc.z), e3 = EXP2(sc.w);
      fragu pf;
      pf.u[0] = pk_bf2(e0, e1);
      pf.u[1] = pk_bf2(e2, e3);
      dacc[3] = MFMA16(ones.s, pf.s, dacc[3]);
      oacc[3] = MFMA16(vf, pf.s, oacc[3]);
    }
  }

#pragma unroll
  for (int s = 0; s < 4; s++) {
    int ti = (s < 3) ? (w + 8 * s) : 24;
    if (s < 3 || w == wx) {
      size_t q = (size_t)strip * 400 + ti * 16 + lm;
      float* np = numw + (((size_t)bh * 4 + kc) * HWSZ + q) * 16 + 4 * qd;
      *(f32x4*)np = oacc[s];
      if (qd == 0) denw[((size_t)bh * 4 + kc) * HWSZ + q] = dacc[s][0];
    }
  }
}

// ---------------- K3: combine attn partials + MFMA linear2 ---------------
// B-frag (ks, qd) spans head h = ks, dims 4qd..4qd+3: combine the 4 key-
// split partials (Σn / Σd) in-register, then 16 MFMAs per ks.
__global__ __launch_bounds__(256) void k3_mfma(
    const float* __restrict__ numw, const float* __restrict__ denw,
    const unsigned short* __restrict__ W2s, const float* __restrict__ b2,
    float* __restrict__ img_out) {
  int t = threadIdx.x, lane = t & 63, w = t >> 6;
  int lm = lane & 15, qd = lane >> 4;
  int blk = blockIdx.x;                      // 200 = 8b x 25 strips of 64
  int b = blk / 25, n0 = (blk % 25) * 64;
  int tok = n0 + w * 16 + lm;
  const s16x4* W2s4 = (const s16x4*)W2s;
  f32x4 acc[16];
#pragma unroll
  for (int ct = 0; ct < 16; ct++) acc[ct] = (f32x4){0.f, 0.f, 0.f, 0.f};
#pragma unroll 2
  for (int ks = 0; ks < 8; ks++) {
    size_t bh4 = (size_t)(b * 8 + ks) * 4;
    const float* npb = numw + (bh4 * HWSZ + tok) * 16 + 4 * qd;
    const float* dpb = denw + bh4 * HWSZ + tok;
    f32x4 nv0 = *(const f32x4*)npb;
    f32x4 nv1 = *(const f32x4*)(npb + (size_t)HWSZ * 16);
    f32x4 nv2 = *(const f32x4*)(npb + (size_t)HWSZ * 32);
    f32x4 nv3 = *(const f32x4*)(npb + (size_t)HWSZ * 48);
    float d = dpb[0] + dpb[HWSZ] + dpb[2 * HWSZ] + dpb[3 * HWSZ];
    float inv = 1.f / d;
    f32x4 nv;
    nv.x = (nv0.x + nv1.x) + (nv2.x + nv3.x);
    nv.y = (nv0.y + nv1.y) + (nv2.y + nv3.y);
    nv.z = (nv0.z + nv1.z) + (nv2.z + nv3.z);
    nv.w = (nv0.w + nv1.w) + (nv2.w + nv3.w);
    fragu bf_;
    bf_.u[0] = pk_bf2(nv.x * inv, nv.y * inv);
    bf_.u[1] = pk_bf2(nv.z * inv, nv.w * inv);
#pragma unroll
    for (int ct = 0; ct < 16; ct++) {
      s16x4 af = W2s4[(ct * 8 + ks) * 64 + lane];
      acc[ct] = MFMA16(af, bf_.s, acc[ct]);
    }
  }
  float* ob = img_out + (size_t)b * CI * HWSZ;
#pragma unroll
  for (int ct = 0; ct < 16; ct++)
#pragma unroll
    for (int r = 0; r < 4; r++) {
      int ci = ct * 16 + 4 * qd + r;
      ob[(size_t)ci * HWSZ + tok] = acc[ct][r] + b2[ci];
    }
}

// ---------------- KPOST: image GeM rows (float4) + cloud GeM combine -----
// Image: one wave per row, float4 loads. Cloud: 4 blocks x 64 float4-slots
// x 4 k-chunks, coalesced float4 loads, LDS combine (R9-proven).
__global__ __launch_bounds__(256) void kpost(
    const float* __restrict__ img_out, const float* __restrict__ gaw,
    const float* __restrict__ cntw, float* __restrict__ image_gem,
    float* __restrict__ cloud_gem) {
  __shared__ float cs[2];
  __shared__ float4 part[3][64];
  int t = threadIdx.x;
  int w = t >> 6, lane = t & 63;
  if (blockIdx.x < 512) {
    int row = blockIdx.x * 4 + w;            // 2048 rows of 1600 (=400 float4)
    const float4* r4 = (const float4*)(img_out + (size_t)row * HWSZ);
    float s = 0.f;
    for (int i = lane; i < 400; i += 64) {
      float4 v = r4[i];
      float c0 = fmaxf(v.x, 1e-6f), c1 = fmaxf(v.y, 1e-6f);
      float c2 = fmaxf(v.z, 1e-6f), c3 = fmaxf(v.w, 1e-6f);
      s += (c0*c0*c0 + c1*c1*c1) + (c2*c2*c2 + c3*c3*c3);
    }
    s += __shfl_xor(s, 1);  s += __shfl_xor(s, 2);  s += __shfl_xor(s, 4);
    s += __shfl_xor(s, 8);  s += __shfl_xor(s, 16); s += __shfl_xor(s, 32);
    if (lane == 0) image_gem[row] = powf(s * (1.f / (float)HWSZ), 1.f / 3.f);
  } else {
    int bb = blockIdx.x - 512;               // 0..3: j range bb*256..bb*256+255
    int sl = lane;                           // local slot 0..63
    int slot = bb * 64 + sl;                 // global float4-slot 0..255
    int kc = w;                              // k-chunk 0..3
    const float4* g4 = (const float4*)gaw;   // [256 blocks][256 float4]
    float4 s4 = make_float4(0.f, 0.f, 0.f, 0.f);
#pragma unroll 4
    for (int k = kc * 64; k < kc * 64 + 64; k++) {
      float4 v = g4[(size_t)k * 256 + slot];
      s4.x += v.x; s4.y += v.y; s4.z += v.z; s4.w += v.w;
    }
    // counts: waves 0,1 each reduce one batch's 256 cntw entries
    if (w < 2) {
      int b = 2 * bb + w;
      float c = 0.f;
#pragma unroll 4
      for (int k = lane; k < 256; k += 64) c += cntw[k * 8 + b];
      c += __shfl_xor(c, 1);  c += __shfl_xor(c, 2);  c += __shfl_xor(c, 4);
      c += __shfl_xor(c, 8);  c += __shfl_xor(c, 16); c += __shfl_xor(c, 32);
      if (lane == 0) cs[w] = c;
    }
    if (kc != 0) part[kc - 1][sl] = s4;
    __syncthreads();
    if (kc == 0) {
      float4 p0 = part[0][sl], p1 = part[1][sl], p2 = part[2][sl];
      s4.x += (p0.x + p1.x) + p2.x;
      s4.y += (p0.y + p1.y) + p2.y;
      s4.z += (p0.z + p1.z) + p2.z;
      s4.w += (p0.w + p1.w) + p2.w;
      float inv = 1.f / fmaxf(cs[sl >> 5], 1.f);
      int j = slot * 4;
      cloud_gem[j + 0] = powf(s4.x * inv, 1.f / 3.f);
      cloud_gem[j + 1] = powf(s4.y * inv, 1.f / 3.f);
      cloud_gem[j + 2] = powf(s4.z * inv, 1.f / 3.f);
      cloud_gem[j + 3] = powf(s4.w * inv, 1.f / 3.f);
    }
  }
}

extern "C" void kernel_launch(void* const* d_in, const int* in_sizes, int n_in,
                              void* d_out, int out_size, void* d_ws, size_t ws_size,
                              hipStream_t stream) {
  const float* image_feat = (const float*)d_in[0];
  const float* cloud_feat = (const float*)d_in[1];
  const int*   cloud_bids = (const int*)d_in[2];
  const float* W1 = (const float*)d_in[3];
  const float* b1 = (const float*)d_in[4];
  const float* W2 = (const float*)d_in[5];
  const float* b2 = (const float*)d_in[6];

  float* out = (float*)d_out;
  float* img_out   = out;                                  // [8,256,40,40]
  float* cloud_out = out + 3276800;                        // [32768,128]
  float* image_gem = out + 3276800 + 4194304;              // [8,256]
  float* cloud_gem = image_gem + 2048;                     // [8,128]

  char* ws = (char*)d_ws;
  unsigned short* tokh = (unsigned short*)ws;              //  3,276,800 B
  float* numw = (float*)(ws + 3276800);                    // 26,214,400 B
  float* denw = (float*)(ws + 29491200);                   //  1,638,400 B
  unsigned short* W1s = (unsigned short*)(ws + 31129600);  //     65,536 B
  unsigned short* W2s = (unsigned short*)(ws + 31195136);  //     65,536 B
  float* gaw  = (float*)(ws + 31260672);                   //  1,048,576 B
  float* cntw = (float*)(ws + 32309248);                   //      8,192 B

  kprep<<<dim3(64), dim3(256), 0, stream>>>(W1, W2, W1s, W2s);
  k1_mfma<<<dim3(456), dim3(256), 0, stream>>>(image_feat, W1s, b1, tokh,
                                               cloud_feat, cloud_bids,
                                               cloud_out, gaw, cntw);
  k2_attn<<<dim3(256, 4), dim3(512), 0, stream>>>(tokh, numw, denw);
  k3_mfma<<<dim3(200), dim3(256), 0, stream>>>(numw, denw, W2s, b2, img_out);
  kpost<<<dim3(516), dim3(256), 0, stream>>>(img_out, gaw, cntw,
                                             image_gem, cloud_gem);
}

// Round 11
// 162.157 us; speedup vs baseline: 1.3235x; 1.0063x over previous
//
#include <hip/hip_runtime.h>
#include <hip/hip_bf16.h>
#include <math.h>

#define BATCH 8
#define CI    256
#define HWSZ  1600
#define DDIM  128
#define NHEAD 8
#define DH    16
#define NPTS  32768

typedef __attribute__((ext_vector_type(4))) short s16x4;
typedef __attribute__((ext_vector_type(4))) float f32x4;

#if defined(__HIP_DEVICE_COMPILE__)
  #if __has_builtin(__builtin_amdgcn_mfma_f32_16x16x16bf16_1k)
    #define MFMA16(a, b, c) __builtin_amdgcn_mfma_f32_16x16x16bf16_1k(a, b, c, 0, 0, 0)
  #elif __has_builtin(__builtin_amdgcn_mfma_f32_16x16x16_bf16)
    #define MFMA16(a, b, c) __builtin_amdgcn_mfma_f32_16x16x16_bf16(a, b, c, 0, 0, 0)
  #else
    #error "no 16x16x16 bf16 mfma builtin on this device target"
  #endif
  #if __has_builtin(__builtin_amdgcn_exp2f)
    #define EXP2(x) __builtin_amdgcn_exp2f(x)
  #else
    #define EXP2(x) exp2f(x)
  #endif
  #define SETPRIO(n) __builtin_amdgcn_s_setprio(n)
#else
  #define MFMA16(a, b, c) (c)
  #define EXP2(x) (x)
  #define SETPRIO(n)
#endif

union fragu {
  s16x4 s;
  unsigned int u[2];
  uint2 u2;
};

__device__ __forceinline__ unsigned int pk_bf2(float a, float b) {
  __hip_bfloat162 h = __float22bfloat162_rn(make_float2(a, b));
  return *(unsigned int*)&h;
}
__device__ __forceinline__ float bf2f(unsigned short u) {
  return __uint_as_float(((unsigned int)u) << 16);
}

// ---------------- KPREP: 64 blocks of weight gather only -----------------
// W1s[dt][ks][lane]: A-frag bf16 of W1^T; W2s[ct][ks][lane]: A-frag of W2^T.
__global__ __launch_bounds__(256) void kprep(
    const float* __restrict__ W1, const float* __restrict__ W2,
    unsigned short* __restrict__ W1s, unsigned short* __restrict__ W2s) {
  int t = threadIdx.x;
  int e = blockIdx.x * 256 + t;             // 16384 entries
  int lane = e & 63, lm = lane & 15, qd = lane >> 4;
  if (e < 8192) {
    int ks = (e >> 6) & 15, dt = e >> 10;
    const float* p = W1 + (size_t)(ks * 16 + 4 * qd) * DDIM + dt * 16 + lm;
    float f0 = p[0], f1 = p[DDIM], f2 = p[2 * DDIM], f3 = p[3 * DDIM];
    *(uint2*)&W1s[(size_t)e * 4] = make_uint2(pk_bf2(f0, f1), pk_bf2(f2, f3));
  } else {
    int e2 = e - 8192;
    int ks = (e2 >> 6) & 7, ct = e2 >> 9;
    const float* p = W2 + (size_t)(ks * 16 + 4 * qd) * CI + ct * 16 + lm;
    float f0 = p[0], f1 = p[CI], f2 = p[2 * CI], f3 = p[3 * CI];
    *(uint2*)&W2s[(size_t)e2 * 4] = make_uint2(pk_bf2(f0, f1), pk_bf2(f2, f3));
  }
}

// ---------------- K1: MFMA linear1 + l2norm -> tokh; + cloud branch ------
// blocks 0..199: image branch (4 waves, full B-prefetch before MFMA chain).
// blocks 200..455: cloud branch (l2norm + per-block GeM partials) — fused
// here so the cloud work runs on the CUs k1's 200 blocks leave idle.
__global__ __launch_bounds__(256) void k1_mfma(
    const float* __restrict__ img, const unsigned short* __restrict__ W1s,
    const float* __restrict__ b1, unsigned short* __restrict__ tokh,
    const float* __restrict__ cf, const int* __restrict__ bids,
    float* __restrict__ cloud_out, float* __restrict__ gaw,
    float* __restrict__ cntw) {
  __shared__ float ga[BATCH * DDIM];
  __shared__ float gc[BATCH];
  int t = threadIdx.x;
  if (blockIdx.x >= 200) {
    // ---------- cloud branch ----------
    int bk = blockIdx.x - 200;               // 0..255, 128 rows each
    for (int i = t; i < BATCH * DDIM; i += 256) ga[i] = 0.f;
    if (t < BATCH) gc[t] = 0.f;
    __syncthreads();
    for (int half = 0; half < 2; half++) {
      int r = bk * 128 + half * 64 + (t >> 2);
      int dq = (t & 3) * 32;
      const float* row = cf + (size_t)r * DDIM + dq;
      float4 v[8];
      float ss = 0.f;
#pragma unroll
      for (int j = 0; j < 8; j++) {
        v[j] = *(const float4*)(row + j * 4);
        ss += v[j].x*v[j].x + v[j].y*v[j].y + v[j].z*v[j].z + v[j].w*v[j].w;
      }
      ss += __shfl_xor(ss, 1);
      ss += __shfl_xor(ss, 2);
      float sc = 1.f / fmaxf(sqrtf(ss), 1e-12f);
      int bid = bids[r];
      if ((t & 3) == 0) atomicAdd(&gc[bid], 1.f);
      float* orow = cloud_out + (size_t)r * DDIM + dq;
      float* gb = &ga[bid * DDIM + dq];
#pragma unroll
      for (int j = 0; j < 8; j++) {
        float4 y;
        y.x = v[j].x * sc; y.y = v[j].y * sc; y.z = v[j].z * sc; y.w = v[j].w * sc;
        *(float4*)(orow + j * 4) = y;
        float c0 = fmaxf(y.x, 1e-6f), c1 = fmaxf(y.y, 1e-6f);
        float c2 = fmaxf(y.z, 1e-6f), c3 = fmaxf(y.w, 1e-6f);
        atomicAdd(&gb[j*4+0], c0*c0*c0);
        atomicAdd(&gb[j*4+1], c1*c1*c1);
        atomicAdd(&gb[j*4+2], c2*c2*c2);
        atomicAdd(&gb[j*4+3], c3*c3*c3);
      }
    }
    __syncthreads();
    for (int i = t; i < BATCH * DDIM; i += 256) gaw[(size_t)bk * 1024 + i] = ga[i];
    if (t < BATCH) cntw[bk * 8 + t] = gc[t];
    return;
  }
  // ---------- image branch ----------
  int lane = t & 63, w = t >> 6;
  int lm = lane & 15, qd = lane >> 4;
  int blk = blockIdx.x;                      // 200 = 8b x 25 strips of 64
  int b = blk / 25, n0 = (blk % 25) * 64;
  int tok = n0 + w * 16 + lm;
  const float* imgb = img + (size_t)b * CI * HWSZ;
  const s16x4* W1s4 = (const s16x4*)W1s;
  float fv[16][4];
#pragma unroll
  for (int ks = 0; ks < 16; ks++) {
    const float* p = imgb + (size_t)(ks * 16 + 4 * qd) * HWSZ + tok;
    fv[ks][0] = p[0];        fv[ks][1] = p[HWSZ];
    fv[ks][2] = p[2 * HWSZ]; fv[ks][3] = p[3 * HWSZ];
  }
  f32x4 acc[8];
#pragma unroll
  for (int dt = 0; dt < 8; dt++) acc[dt] = (f32x4){0.f, 0.f, 0.f, 0.f};
#pragma unroll
  for (int ks = 0; ks < 16; ks++) {
    fragu bf_;
    bf_.u[0] = pk_bf2(fv[ks][0], fv[ks][1]);
    bf_.u[1] = pk_bf2(fv[ks][2], fv[ks][3]);
#pragma unroll
    for (int dt = 0; dt < 8; dt++) {
      s16x4 af = W1s4[(dt * 16 + ks) * 64 + lane];
      acc[dt] = MFMA16(af, bf_.s, acc[dt]);
    }
  }
  float vals[8][4];
  float ss = 0.f;
#pragma unroll
  for (int dt = 0; dt < 8; dt++)
#pragma unroll
    for (int r = 0; r < 4; r++) {
      float v = acc[dt][r] + b1[dt * 16 + 4 * qd + r];
      vals[dt][r] = v;
      ss += v * v;
    }
  ss += __shfl_xor(ss, 16);
  ss += __shfl_xor(ss, 32);
  float inv = 1.f / fmaxf(sqrtf(ss), 1e-12f);
#pragma unroll
  for (int dt = 0; dt < 8; dt++) {
    uint2 pk = make_uint2(pk_bf2(vals[dt][0] * inv, vals[dt][1] * inv),
                          pk_bf2(vals[dt][2] * inv, vals[dt][3] * inv));
    *(uint2*)&tokh[(((size_t)b * NHEAD + dt) * HWSZ + tok) * DH + 4 * qd] = pk;
  }
}

// ---------------- K2: MFMA flash attention, key-split 4x (R4 winner) -----
// grid (256,4): x = bh*4 + kc. Each 8-wave block stages 400 keys (32.25 KB
// LDS) -> 4 blocks/CU = 32 waves/CU = 8 waves/SIMD (HW cap). Balanced
// q-tiling: 25 tiles of 16; every wave runs 3 chains (ti = w+8s), one
// rotated wave (w == wx) takes tile 24. den accumulated on the MFMA pipe
// via ones-fragment; (num, den) partials combined in k3.
// This round: unroll 5 (25 = 5x5, no remainder) + s_setprio around the
// den/PV MFMA pairs — k2's hot loop has no barriers, so waves sit at
// different phases and priority arbitration can favor MFMA-entering waves
// (the regime where setprio measured +4-7%; null only in barrier-locked
// loops).
#define NKC4     400
#define XK_STR   24
#define VT_STR   408
__global__ __launch_bounds__(512) void k2_attn(
    const unsigned short* __restrict__ tokh, float* __restrict__ numw,
    float* __restrict__ denw) {
  __shared__ unsigned short sXk[NKC4 * XK_STR];   // 19200 B
  __shared__ unsigned short sVt[16 * VT_STR];     // 13056 B -> 32256 B total
  const int gx = blockIdx.x;
  const int bh = gx >> 2, kc = gx & 3;
  const int strip = blockIdx.y;                   // 0..3, 400 queries each
  const int t = threadIdx.x;
  const int lane = t & 63;
  const int w = t >> 6;                           // 0..7
  const int lm = lane & 15;
  const int qd = lane >> 4;
  const int wx = (kc + strip * 4) & 7;            // wave owning tile 24
  const unsigned short* tok = tokh + (size_t)bh * (HWSZ * DH);

  // stage this block's 400 keys (token-major for K, dim-major for V^T)
  for (int r = t; r < NKC4; r += 512) {
    const uint4* src = (const uint4*)(tok + (size_t)(kc * NKC4 + r) * DH);
    union { uint4 u4[2]; unsigned short us[16]; } uu;
    uu.u4[0] = src[0]; uu.u4[1] = src[1];
    *(uint4*)&sXk[r * XK_STR]     = uu.u4[0];
    *(uint4*)&sXk[r * XK_STR + 8] = uu.u4[1];
#pragma unroll
    for (int d = 0; d < 16; d++) sVt[d * VT_STR + r] = uu.us[d];
  }

  const float SCL = 0.25f * 1.44269504088896f;
  s16x4 qf[4];
  f32x4 oacc[4], dacc[4];
#pragma unroll
  for (int s = 0; s < 4; s++) {
    oacc[s] = (f32x4){0.f, 0.f, 0.f, 0.f};
    dacc[s] = (f32x4){0.f, 0.f, 0.f, 0.f};
    int ti = (s < 3) ? (w + 8 * s) : 24;
    if (s < 3 || w == wx) {
      int q = strip * 400 + ti * 16 + lm;
      const unsigned short* qs = tok + (size_t)q * DH + 4 * qd;
      s16x4 raw = *(const s16x4*)qs;
      fragu qq;
      qq.u[0] = pk_bf2(bf2f((unsigned short)raw[0]) * SCL,
                       bf2f((unsigned short)raw[1]) * SCL);
      qq.u[1] = pk_bf2(bf2f((unsigned short)raw[2]) * SCL,
                       bf2f((unsigned short)raw[3]) * SCL);
      qf[s] = qq.s;
    }
  }
  __syncthreads();

  fragu ones;
  ones.u[0] = 0x3F803F80u;  // bf16 1.0 x2
  ones.u[1] = 0x3F803F80u;
#pragma unroll 5
  for (int st = 0; st < NKC4 / 16; st++) {
    int n0 = st * 16;
    s16x4 kf = *(const s16x4*)&sXk[(n0 + lm) * XK_STR + 4 * qd];
    s16x4 vf = *(const s16x4*)&sVt[lm * VT_STR + n0 + 4 * qd];
#pragma unroll
    for (int s = 0; s < 3; s++) {                 // ti = w+8s <= 23: always valid
      f32x4 sc = MFMA16(kf, qf[s], ((f32x4){0.f, 0.f, 0.f, 0.f}));
      float e0 = EXP2(sc.x), e1 = EXP2(sc.y), e2 = EXP2(sc.z), e3 = EXP2(sc.w);
      fragu pf;
      pf.u[0] = pk_bf2(e0, e1);
      pf.u[1] = pk_bf2(e2, e3);
      SETPRIO(1);
      dacc[s] = MFMA16(ones.s, pf.s, dacc[s]);    // den on the MFMA pipe
      oacc[s] = MFMA16(vf, pf.s, oacc[s]);
      SETPRIO(0);
    }
    if (w == wx) {                                // tile 24: rotated wave only
      f32x4 sc = MFMA16(kf, qf[3], ((f32x4){0.f, 0.f, 0.f, 0.f}));
      float e0 = EXP2(sc.x), e1 = EXP2(sc.y), e2 = EXP2(sc.z), e3 = EXP2(sc.w);
      fragu pf;
      pf.u[0] = pk_bf2(e0, e1);
      pf.u[1] = pk_bf2(e2, e3);
      SETPRIO(1);
      dacc[3] = MFMA16(ones.s, pf.s, dacc[3]);
      oacc[3] = MFMA16(vf, pf.s, oacc[3]);
      SETPRIO(0);
    }
  }

#pragma unroll
  for (int s = 0; s < 4; s++) {
    int ti = (s < 3) ? (w + 8 * s) : 24;
    if (s < 3 || w == wx) {
      size_t q = (size_t)strip * 400 + ti * 16 + lm;
      float* np = numw + (((size_t)bh * 4 + kc) * HWSZ + q) * 16 + 4 * qd;
      *(f32x4*)np = oacc[s];
      if (qd == 0) denw[((size_t)bh * 4 + kc) * HWSZ + q] = dacc[s][0];
    }
  }
}

// ---------------- K3: combine attn partials + MFMA linear2 ---------------
// B-frag (ks, qd) spans head h = ks, dims 4qd..4qd+3: combine the 4 key-
// split partials (Σn / Σd) in-register, then 16 MFMAs per ks.
__global__ __launch_bounds__(256) void k3_mfma(
    const float* __restrict__ numw, const float* __restrict__ denw,
    const unsigned short* __restrict__ W2s, const float* __restrict__ b2,
    float* __restrict__ img_out) {
  int t = threadIdx.x, lane = t & 63, w = t >> 6;
  int lm = lane & 15, qd = lane >> 4;
  int blk = blockIdx.x;                      // 200 = 8b x 25 strips of 64
  int b = blk / 25, n0 = (blk % 25) * 64;
  int tok = n0 + w * 16 + lm;
  const s16x4* W2s4 = (const s16x4*)W2s;
  f32x4 acc[16];
#pragma unroll
  for (int ct = 0; ct < 16; ct++) acc[ct] = (f32x4){0.f, 0.f, 0.f, 0.f};
#pragma unroll 2
  for (int ks = 0; ks < 8; ks++) {
    size_t bh4 = (size_t)(b * 8 + ks) * 4;
    const float* npb = numw + (bh4 * HWSZ + tok) * 16 + 4 * qd;
    const float* dpb = denw + bh4 * HWSZ + tok;
    f32x4 nv0 = *(const f32x4*)npb;
    f32x4 nv1 = *(const f32x4*)(npb + (size_t)HWSZ * 16);
    f32x4 nv2 = *(const f32x4*)(npb + (size_t)HWSZ * 32);
    f32x4 nv3 = *(const f32x4*)(npb + (size_t)HWSZ * 48);
    float d = dpb[0] + dpb[HWSZ] + dpb[2 * HWSZ] + dpb[3 * HWSZ];
    float inv = 1.f / d;
    f32x4 nv;
    nv.x = (nv0.x + nv1.x) + (nv2.x + nv3.x);
    nv.y = (nv0.y + nv1.y) + (nv2.y + nv3.y);
    nv.z = (nv0.z + nv1.z) + (nv2.z + nv3.z);
    nv.w = (nv0.w + nv1.w) + (nv2.w + nv3.w);
    fragu bf_;
    bf_.u[0] = pk_bf2(nv.x * inv, nv.y * inv);
    bf_.u[1] = pk_bf2(nv.z * inv, nv.w * inv);
#pragma unroll
    for (int ct = 0; ct < 16; ct++) {
      s16x4 af = W2s4[(ct * 8 + ks) * 64 + lane];
      acc[ct] = MFMA16(af, bf_.s, acc[ct]);
    }
  }
  float* ob = img_out + (size_t)b * CI * HWSZ;
#pragma unroll
  for (int ct = 0; ct < 16; ct++)
#pragma unroll
    for (int r = 0; r < 4; r++) {
      int ci = ct * 16 + 4 * qd + r;
      ob[(size_t)ci * HWSZ + tok] = acc[ct][r] + b2[ci];
    }
}

// ---------------- KPOST: image GeM rows (float4) + cloud GeM combine -----
__global__ __launch_bounds__(256) void kpost(
    const float* __restrict__ img_out, const float* __restrict__ gaw,
    const float* __restrict__ cntw, float* __restrict__ image_gem,
    float* __restrict__ cloud_gem) {
  __shared__ float cs[2];
  __shared__ float4 part[3][64];
  int t = threadIdx.x;
  int w = t >> 6, lane = t & 63;
  if (blockIdx.x < 512) {
    int row = blockIdx.x * 4 + w;            // 2048 rows of 1600 (=400 float4)
    const float4* r4 = (const float4*)(img_out + (size_t)row * HWSZ);
    float s = 0.f;
    for (int i = lane; i < 400; i += 64) {
      float4 v = r4[i];
      float c0 = fmaxf(v.x, 1e-6f), c1 = fmaxf(v.y, 1e-6f);
      float c2 = fmaxf(v.z, 1e-6f), c3 = fmaxf(v.w, 1e-6f);
      s += (c0*c0*c0 + c1*c1*c1) + (c2*c2*c2 + c3*c3*c3);
    }
    s += __shfl_xor(s, 1);  s += __shfl_xor(s, 2);  s += __shfl_xor(s, 4);
    s += __shfl_xor(s, 8);  s += __shfl_xor(s, 16); s += __shfl_xor(s, 32);
    if (lane == 0) image_gem[row] = powf(s * (1.f / (float)HWSZ), 1.f / 3.f);
  } else {
    int bb = blockIdx.x - 512;               // 0..3: j range bb*256..bb*256+255
    int sl = lane;                           // local slot 0..63
    int slot = bb * 64 + sl;                 // global float4-slot 0..255
    int kc = w;                              // k-chunk 0..3
    const float4* g4 = (const float4*)gaw;   // [256 blocks][256 float4]
    float4 s4 = make_float4(0.f, 0.f, 0.f, 0.f);
#pragma unroll 4
    for (int k = kc * 64; k < kc * 64 + 64; k++) {
      float4 v = g4[(size_t)k * 256 + slot];
      s4.x += v.x; s4.y += v.y; s4.z += v.z; s4.w += v.w;
    }
    // counts: waves 0,1 each reduce one batch's 256 cntw entries
    if (w < 2) {
      int b = 2 * bb + w;
      float c = 0.f;
#pragma unroll 4
      for (int k = lane; k < 256; k += 64) c += cntw[k * 8 + b];
      c += __shfl_xor(c, 1);  c += __shfl_xor(c, 2);  c += __shfl_xor(c, 4);
      c += __shfl_xor(c, 8);  c += __shfl_xor(c, 16); c += __shfl_xor(c, 32);
      if (lane == 0) cs[w] = c;
    }
    if (kc != 0) part[kc - 1][sl] = s4;
    __syncthreads();
    if (kc == 0) {
      float4 p0 = part[0][sl], p1 = part[1][sl], p2 = part[2][sl];
      s4.x += (p0.x + p1.x) + p2.x;
      s4.y += (p0.y + p1.y) + p2.y;
      s4.z += (p0.z + p1.z) + p2.z;
      s4.w += (p0.w + p1.w) + p2.w;
      float inv = 1.f / fmaxf(cs[sl >> 5], 1.f);
      int j = slot * 4;
      cloud_gem[j + 0] = powf(s4.x * inv, 1.f / 3.f);
      cloud_gem[j + 1] = powf(s4.y * inv, 1.f / 3.f);
      cloud_gem[j + 2] = powf(s4.z * inv, 1.f / 3.f);
      cloud_gem[j + 3] = powf(s4.w * inv, 1.f / 3.f);
    }
  }
}

extern "C" void kernel_launch(void* const* d_in, const int* in_sizes, int n_in,
                              void* d_out, int out_size, void* d_ws, size_t ws_size,
                              hipStream_t stream) {
  const float* image_feat = (const float*)d_in[0];
  const float* cloud_feat = (const float*)d_in[1];
  const int*   cloud_bids = (const int*)d_in[2];
  const float* W1 = (const float*)d_in[3];
  const float* b1 = (const float*)d_in[4];
  const float* W2 = (const float*)d_in[5];
  const float* b2 = (const float*)d_in[6];

  float* out = (float*)d_out;
  float* img_out   = out;                                  // [8,256,40,40]
  float* cloud_out = out + 3276800;                        // [32768,128]
  float* image_gem = out + 3276800 + 4194304;              // [8,256]
  float* cloud_gem = image_gem + 2048;                     // [8,128]

  char* ws = (char*)d_ws;
  unsigned short* tokh = (unsigned short*)ws;              //  3,276,800 B
  float* numw = (float*)(ws + 3276800);                    // 26,214,400 B
  float* denw = (float*)(ws + 29491200);                   //  1,638,400 B
  unsigned short* W1s = (unsigned short*)(ws + 31129600);  //     65,536 B
  unsigned short* W2s = (unsigned short*)(ws + 31195136);  //     65,536 B
  float* gaw  = (float*)(ws + 31260672);                   //  1,048,576 B
  float* cntw = (float*)(ws + 32309248);                   //      8,192 B

  kprep<<<dim3(64), dim3(256), 0, stream>>>(W1, W2, W1s, W2s);
  k1_mfma<<<dim3(456), dim3(256), 0, stream>>>(image_feat, W1s, b1, tokh,
                                               cloud_feat, cloud_bids,
                                               cloud_out, gaw, cntw);
  k2_attn<<<dim3(256, 4), dim3(512), 0, stream>>>(tokh, numw, denw);
  k3_mfma<<<dim3(200), dim3(256), 0, stream>>>(numw, denw, W2s, b2, img_out);
  kpost<<<dim3(516), dim3(256), 0, stream>>>(img_out, gaw, cntw,
                                             image_gem, cloud_gem);
}